// Round 4
// baseline (66.275 us; speedup 1.0000x reference)
//
#include <hip/hip_runtime.h>
#include <stdint.h>

#define NN 2048
#define TPB 256
#define EPT 8          // NN / TPB
#define KNB 16
#define CAP 128        // candidate capacity (power-of-two not required; <= TPB)
#define CAPPAD (CAP + 8)

static constexpr unsigned long long EXCL = ~0ull;
// Threshold 0.046875f (= 3/64): dist_bits < 0x3D400000 -> candidate.
// ~1024 unblocked entries/row, P(candidate) = 3/64 -> c ~ Bin(1024, 3/64):
// mean 48, sigma 6.8; P(c<16) ~ 7e-7, P(c>128) ~ 0. Both -> exact fallback.
static constexpr unsigned long long T0KEY = ((unsigned long long)0x3D400000u) << 11;

__global__ __launch_bounds__(TPB, 8) void encoder_mask_kernel(
    const float* __restrict__ D,      // [B,N,N]
    const int*   __restrict__ TWC,    // [B,N,N]
    const int*   __restrict__ depot,  // [B,N]
    float*       __restrict__ out)    // [B,N,N]
{
    const int row = blockIdx.x;       // b*N + i
    const int b   = row >> 11;
    const int i   = row & (NN - 1);
    const int t   = threadIdx.x;
    const int j0  = t * EPT;

    float*       orow   = out + (size_t)row * NN;
    const int*   deprow = depot + b * NN;

    // Issue depot loads early; consumed only in the tail (or ignored on fast path).
    const int4 p0 = reinterpret_cast<const int4*>(deprow + j0)[0];
    const int4 p1 = reinterpret_cast<const int4*>(deprow + j0)[1];
    const int  depot_i = deprow[i];   // block-uniform: branch below is safe w.r.t. barriers

    // Fast path: depot[b,i]==1 -> entire row is ones; skip all reads of D/TWC.
    if (depot_i != 0) {
        const float4 ones = make_float4(1.f, 1.f, 1.f, 1.f);
        float4* o4 = reinterpret_cast<float4*>(orow + j0);
        o4[0] = ones;
        o4[1] = ones;
        return;
    }

    const float* drow = D   + (size_t)row * NN;
    const int*   trow = TWC + (size_t)row * NN;

    // Issue the heavy loads immediately; LDS init below hides under their latency.
    const float4 d0 = reinterpret_cast<const float4*>(drow + j0)[0];
    const float4 d1 = reinterpret_cast<const float4*>(drow + j0)[1];
    const int4   c0 = reinterpret_cast<const int4*>(trow + j0)[0];
    const int4   c1 = reinterpret_cast<const int4*>(trow + j0)[1];

    __shared__ unsigned long long cand[CAPPAD];
    __shared__ unsigned long long selq[TPB];   // 2048-byte selected bytemap
    __shared__ unsigned long long wpart[2][TPB / 64];
    __shared__ int cnt;

    selq[t] = 0ull;
    if (t < CAPPAD) cand[t] = EXCL;            // pre-pad: rank loop reads up to c+7
    if (t == 0) cnt = 0;
    __syncthreads();

    const float dv[EPT] = {d0.x, d0.y, d0.z, d0.w, d1.x, d1.y, d1.z, d1.w};
    const int   cv[EPT] = {c0.x, c0.y, c0.z, c0.w, c1.x, c1.y, c1.z, c1.w};

    // Sortable keys: (dist_bits << 11) | j ; excluded -> EXCL. dist in [0,1) ->
    // bits < 2^30 -> key < 2^41. Index bits make keys unique (exact tie-break,
    // matching lax.top_k's lowest-index-first on equal distances).
    unsigned long long key[EPT];
    #pragma unroll
    for (int k = 0; k < EPT; ++k) {
        const int j = j0 + k;
        const bool excl = (cv[k] == 0) | (j == i);
        key[k] = excl ? EXCL
                      : ((((unsigned long long)__float_as_uint(dv[k])) << 11) |
                         (unsigned long long)(unsigned)j);
    }

    // Filter: gather local sub-threshold keys, reserve slots with ONE atomic.
    unsigned long long loc[EPT];
    int nloc = 0;
    #pragma unroll
    for (int k = 0; k < EPT; ++k) {
        if (key[k] < T0KEY) loc[nloc++] = key[k];
    }
    if (nloc > 0) {
        const int base = atomicAdd(&cnt, nloc);
        #pragma unroll 1
        for (int m = 0; m < nloc; ++m) {
            const int p = base + m;
            if (p < CAP) cand[p] = loc[m];
        }
    }
    __syncthreads();

    const int c = cnt;

    if (c >= KNB && c <= CAP) {
        // Exactness: c >= 16 keys below T0 -> global 16 smallest all in cand[].
        // Rank selection, 8 keys per dependency group (4x ds_read_b128, uniform
        // address -> LDS broadcast, no conflicts).
        if (t < c) {
            const unsigned long long mykey = cand[t];
            int rank = 0;
            const int cround = (c + 7) & ~7;
            #pragma unroll 1
            for (int q = 0; q < cround; q += 8) {
                const ulonglong2 a0 = *reinterpret_cast<const ulonglong2*>(&cand[q]);
                const ulonglong2 a1 = *reinterpret_cast<const ulonglong2*>(&cand[q + 2]);
                const ulonglong2 a2 = *reinterpret_cast<const ulonglong2*>(&cand[q + 4]);
                const ulonglong2 a3 = *reinterpret_cast<const ulonglong2*>(&cand[q + 6]);
                rank += (a0.x < mykey) ? 1 : 0;
                rank += (a0.y < mykey) ? 1 : 0;
                rank += (a1.x < mykey) ? 1 : 0;
                rank += (a1.y < mykey) ? 1 : 0;
                rank += (a2.x < mykey) ? 1 : 0;
                rank += (a2.y < mykey) ? 1 : 0;
                rank += (a3.x < mykey) ? 1 : 0;
                rank += (a3.y < mykey) ? 1 : 0;
            }
            if (rank < KNB) {
                reinterpret_cast<unsigned char*>(selq)[(int)(mykey & 2047u)] = 1;
            }
        }
    } else {
        // Exact fallback (astronomically rare; required for correctness):
        // iterative global-min extraction, K rounds.
        const int wave = t >> 6;
        const int lane = t & 63;
        unsigned long long lmin = key[0];
        #pragma unroll
        for (int k = 1; k < EPT; ++k) lmin = (key[k] < lmin) ? key[k] : lmin;

        #pragma unroll 1
        for (int it = 0; it < KNB; ++it) {
            unsigned long long w = lmin;
            #pragma unroll
            for (int off = 32; off >= 1; off >>= 1) {
                const unsigned long long o = __shfl_xor(w, off);
                w = (o < w) ? o : w;
            }
            const int p = it & 1;
            if (lane == 0) wpart[p][wave] = w;
            __syncthreads();
            unsigned long long g = wpart[p][0];
            {
                const unsigned long long g1 = wpart[p][1];
                const unsigned long long g2 = wpart[p][2];
                const unsigned long long g3 = wpart[p][3];
                g = (g1 < g) ? g1 : g;
                g = (g2 < g) ? g2 : g;
                g = (g3 < g) ? g3 : g;
            }
            if (g == EXCL) break;
            const int jwin = (int)(g & 2047u);
            if (t == 0) reinterpret_cast<unsigned char*>(selq)[jwin] = 1;
            if (lmin == g) {
                unsigned long long nm = EXCL;
                #pragma unroll
                for (int k = 0; k < EPT; ++k) {
                    if (key[k] == g) key[k] = EXCL;
                    nm = (key[k] < nm) ? key[k] : nm;
                }
                lmin = nm;
            }
        }
    }
    __syncthreads();  // sel-bytemap visible to all

    // Output: depot_i==0 here, so mask = depot_j | (j==i) | selected(j).
    const unsigned long long selbits = selq[t];
    const int dpv[EPT] = {p0.x, p0.y, p0.z, p0.w, p1.x, p1.y, p1.z, p1.w};

    float ov[EPT];
    #pragma unroll
    for (int k = 0; k < EPT; ++k) {
        const int j = j0 + k;
        const bool sel = ((selbits >> (8 * k)) & 0xffull) != 0ull;
        const bool one = (dpv[k] != 0) | (j == i) | sel;
        ov[k] = one ? 1.0f : 0.0f;
    }
    float4* o4 = reinterpret_cast<float4*>(orow + j0);
    o4[0] = make_float4(ov[0], ov[1], ov[2], ov[3]);
    o4[1] = make_float4(ov[4], ov[5], ov[6], ov[7]);
}

extern "C" void kernel_launch(void* const* d_in, const int* in_sizes, int n_in,
                              void* d_out, int out_size, void* d_ws, size_t ws_size,
                              hipStream_t stream) {
    const float* D     = (const float*)d_in[0];   // distance_matrix [B,N,N]
    // d_in[1] = max_dist — provably irrelevant (blocked entries never survive)
    const int*   TWC   = (const int*)d_in[2];     // time_window_compatibility [B,N,N]
    const int*   depot = (const int*)d_in[3];     // depot [B,N]
    // d_in[4] = num_neighbors_encoder == 16 (compile-time KNB)

    float* outp = (float*)d_out;
    const int rows = in_sizes[3];                 // B*N = 16384

    encoder_mask_kernel<<<rows, TPB, 0, stream>>>(D, TWC, depot, outp);
}

// Round 5
// 48.141 us; speedup vs baseline: 1.3767x; 1.3767x over previous
//
#include <hip/hip_runtime.h>
#include <stdint.h>

#define NN 2048
#define TPB 256
#define EPT 8          // NN / TPB
#define KNB 16
#define CAP 128        // candidate capacity (<= TPB so one thread per candidate)
#define CAPPAD (CAP + 8)

static constexpr unsigned long long EXCL = ~0ull;
// Threshold 0.046875f (= 3/64): dist_bits < 0x3D400000 -> candidate.
// ~1024 unblocked entries/row, P(candidate) = 3/64 -> c ~ Bin(1024, 3/64):
// mean 48, sigma 6.8; P(c<16) ~ 7e-7, P(c>128) ~ 0. Both -> exact fallback.
static constexpr unsigned long long T0KEY = ((unsigned long long)0x3D400000u) << 11;

__global__ __launch_bounds__(TPB) void encoder_mask_kernel(
    const float* __restrict__ D,      // [B,N,N]
    const int*   __restrict__ TWC,    // [B,N,N]
    const int*   __restrict__ depot,  // [B,N]
    float*       __restrict__ out)    // [B,N,N]
{
    const int row = blockIdx.x;       // b*N + i
    const int b   = row >> 11;
    const int i   = row & (NN - 1);
    const int t   = threadIdx.x;
    const int j0  = t * EPT;

    float*       orow   = out + (size_t)row * NN;
    const int*   deprow = depot + b * NN;

    // depot is 64 KB total -> L2-resident; issue these early so the tail has them.
    const int4 p0 = reinterpret_cast<const int4*>(deprow + j0)[0];
    const int4 p1 = reinterpret_cast<const int4*>(deprow + j0)[1];
    const int  depot_i = deprow[i];   // block-uniform -> branch safe w.r.t. barriers

    // Fast path: depot[b,i]==1 -> entire row is ones; skip all reads of D/TWC.
    if (depot_i != 0) {
        const float4 ones = make_float4(1.f, 1.f, 1.f, 1.f);
        float4* o4 = reinterpret_cast<float4*>(orow + j0);
        o4[0] = ones;
        o4[1] = ones;
        return;
    }

    const float* drow = D   + (size_t)row * NN;
    const int*   trow = TWC + (size_t)row * NN;

    // Issue the heavy loads immediately; LDS init hides under their latency.
    const float4 d0 = reinterpret_cast<const float4*>(drow + j0)[0];
    const float4 d1 = reinterpret_cast<const float4*>(drow + j0)[1];
    const int4   c0 = reinterpret_cast<const int4*>(trow + j0)[0];
    const int4   c1 = reinterpret_cast<const int4*>(trow + j0)[1];

    __shared__ unsigned long long cand[CAPPAD];
    __shared__ unsigned long long selq[TPB];   // 2048-byte selected bytemap
    __shared__ unsigned long long wpart[2][TPB / 64];
    __shared__ int cnt;

    selq[t] = 0ull;
    if (t < CAPPAD) cand[t] = EXCL;            // pad so rank loop can read 8-wide
    if (t == 0) cnt = 0;
    __syncthreads();

    const float dv[EPT] = {d0.x, d0.y, d0.z, d0.w, d1.x, d1.y, d1.z, d1.w};
    const int   cv[EPT] = {c0.x, c0.y, c0.z, c0.w, c1.x, c1.y, c1.z, c1.w};

    // Sortable keys: (dist_bits << 11) | j ; excluded -> EXCL. dist in [0,1) ->
    // bits < 2^30 -> key < 2^41. Index bits make keys unique (exact tie-break,
    // matching lax.top_k's lowest-index-first on equal distances).
    unsigned long long key[EPT];
    #pragma unroll
    for (int k = 0; k < EPT; ++k) {
        const int j = j0 + k;
        const bool excl = (cv[k] == 0) | (j == i);
        key[k] = excl ? EXCL
                      : ((((unsigned long long)__float_as_uint(dv[k])) << 11) |
                         (unsigned long long)(unsigned)j);
    }

    // Filter. Pass 1 (static): count sub-threshold keys. One atomic per thread
    // that has any. Pass 2 (static unroll): place keys at cand[idx++] — runtime
    // index into LDS is fine; NO private runtime-indexed arrays (R4 lesson:
    // loc[nloc++] got lowered to 16 KB/block LDS scratch, 137k bank conflicts).
    int nloc = 0;
    #pragma unroll
    for (int k = 0; k < EPT; ++k) nloc += (key[k] < T0KEY) ? 1 : 0;

    if (nloc > 0) {
        int idx = atomicAdd(&cnt, nloc);
        #pragma unroll
        for (int k = 0; k < EPT; ++k) {
            if (key[k] < T0KEY) {
                if (idx < CAP) cand[idx] = key[k];
                ++idx;
            }
        }
    }
    __syncthreads();

    const int c = cnt;

    if (c >= KNB && c <= CAP) {
        // Exactness: c >= 16 keys below T0 -> the global 16 smallest keys are all
        // in cand[]. Rank selection: thread t owns cand[t]; 8 keys per dependency
        // group via uniform-address ds_read_b128 (LDS broadcast, conflict-free).
        if (t < c) {
            const unsigned long long mykey = cand[t];
            int rank = 0;
            const int cround = (c + 7) & ~7;
            #pragma unroll 1
            for (int q = 0; q < cround; q += 8) {
                const ulonglong2 a0 = *reinterpret_cast<const ulonglong2*>(&cand[q]);
                const ulonglong2 a1 = *reinterpret_cast<const ulonglong2*>(&cand[q + 2]);
                const ulonglong2 a2 = *reinterpret_cast<const ulonglong2*>(&cand[q + 4]);
                const ulonglong2 a3 = *reinterpret_cast<const ulonglong2*>(&cand[q + 6]);
                rank += (a0.x < mykey) ? 1 : 0;
                rank += (a0.y < mykey) ? 1 : 0;
                rank += (a1.x < mykey) ? 1 : 0;
                rank += (a1.y < mykey) ? 1 : 0;
                rank += (a2.x < mykey) ? 1 : 0;
                rank += (a2.y < mykey) ? 1 : 0;
                rank += (a3.x < mykey) ? 1 : 0;
                rank += (a3.y < mykey) ? 1 : 0;
            }
            if (rank < KNB) {
                reinterpret_cast<unsigned char*>(selq)[(int)(mykey & 2047u)] = 1;
            }
        }
    } else {
        // Exact fallback (P ~ 7e-7 per row; required for correctness):
        // iterative global-min extraction, K rounds.
        const int wave = t >> 6;
        const int lane = t & 63;
        unsigned long long lmin = key[0];
        #pragma unroll
        for (int k = 1; k < EPT; ++k) lmin = (key[k] < lmin) ? key[k] : lmin;

        #pragma unroll 1
        for (int it = 0; it < KNB; ++it) {
            unsigned long long w = lmin;
            #pragma unroll
            for (int off = 32; off >= 1; off >>= 1) {
                const unsigned long long o = __shfl_xor(w, off);
                w = (o < w) ? o : w;
            }
            const int p = it & 1;
            if (lane == 0) wpart[p][wave] = w;
            __syncthreads();
            unsigned long long g = wpart[p][0];
            {
                const unsigned long long g1 = wpart[p][1];
                const unsigned long long g2 = wpart[p][2];
                const unsigned long long g3 = wpart[p][3];
                g = (g1 < g) ? g1 : g;
                g = (g2 < g) ? g2 : g;
                g = (g3 < g) ? g3 : g;
            }
            if (g == EXCL) break;
            const int jwin = (int)(g & 2047u);
            if (t == 0) reinterpret_cast<unsigned char*>(selq)[jwin] = 1;
            if (lmin == g) {
                unsigned long long nm = EXCL;
                #pragma unroll
                for (int k = 0; k < EPT; ++k) {
                    if (key[k] == g) key[k] = EXCL;
                    nm = (key[k] < nm) ? key[k] : nm;
                }
                lmin = nm;
            }
        }
    }
    __syncthreads();  // sel-bytemap visible to all

    // Output: depot_i==0 here, so mask = depot_j | (j==i) | selected(j).
    const unsigned long long selbits = selq[t];
    const int dpv[EPT] = {p0.x, p0.y, p0.z, p0.w, p1.x, p1.y, p1.z, p1.w};

    float ov[EPT];
    #pragma unroll
    for (int k = 0; k < EPT; ++k) {
        const int j = j0 + k;
        const bool sel = ((selbits >> (8 * k)) & 0xffull) != 0ull;
        const bool one = (dpv[k] != 0) | (j == i) | sel;
        ov[k] = one ? 1.0f : 0.0f;
    }
    float4* o4 = reinterpret_cast<float4*>(orow + j0);
    o4[0] = make_float4(ov[0], ov[1], ov[2], ov[3]);
    o4[1] = make_float4(ov[4], ov[5], ov[6], ov[7]);
}

extern "C" void kernel_launch(void* const* d_in, const int* in_sizes, int n_in,
                              void* d_out, int out_size, void* d_ws, size_t ws_size,
                              hipStream_t stream) {
    const float* D     = (const float*)d_in[0];   // distance_matrix [B,N,N]
    // d_in[1] = max_dist — provably irrelevant (blocked entries never survive)
    const int*   TWC   = (const int*)d_in[2];     // time_window_compatibility [B,N,N]
    const int*   depot = (const int*)d_in[3];     // depot [B,N]
    // d_in[4] = num_neighbors_encoder == 16 (compile-time KNB)

    float* outp = (float*)d_out;
    const int rows = in_sizes[3];                 // B*N = 16384

    encoder_mask_kernel<<<rows, TPB, 0, stream>>>(D, TWC, depot, outp);
}